// Round 1
// baseline (3971.608 us; speedup 1.0000x reference)
//
#include <hip/hip_runtime.h>

namespace {

constexpr int NN = 64;            // agents (N) == hidden (H) == OBS
constexpr int LD = 72;            // bf16 elems per LDS row (144 B, 16B-aligned)
constexpr float SCALE = 0.125f;   // 1/sqrt(64)

struct Params {
  const float *x, *rnd; const int *idx;
  const float *embed_w, *embed_b;
  const float *ia_wq, *ia_bq, *ia_wk, *ia_bk, *ia_wv, *ia_bv, *ia_wo, *ia_bo;
  const float *c1_wq, *c1_bq, *c1_wk, *c1_bk, *c1_wv, *c1_bv, *c1_wo, *c1_bo;
  const float *c2_wq, *c2_bq, *c2_wk, *c2_bk, *c2_wv, *c2_bv, *c2_wo, *c2_bo;
  const float *msg_w, *msg_b, *st_w, *st_b;
  const float *mean_w, *mean_b, *ls_w, *ls_b;
  float *out; int std_off;
};

__device__ __forceinline__ float asf(unsigned u){ union{unsigned u;float f;} c; c.u=u; return c.f; }
__device__ __forceinline__ unsigned asu(float f){ union{unsigned u;float f;} c; c.f=f; return c.u; }
__device__ __forceinline__ unsigned short f2b(float f){
  unsigned u = asu(f);
  u += 0x7fffu + ((u>>16)&1u);          // round-to-nearest-even
  return (unsigned short)(u>>16);
}
__device__ __forceinline__ void up8(const unsigned short* p, float* o){
  uint4 v = *reinterpret_cast<const uint4*>(p);
  o[0]=asf(v.x<<16); o[1]=asf(v.x&0xffff0000u);
  o[2]=asf(v.y<<16); o[3]=asf(v.y&0xffff0000u);
  o[4]=asf(v.z<<16); o[5]=asf(v.z&0xffff0000u);
  o[6]=asf(v.w<<16); o[7]=asf(v.w&0xffff0000u);
}

template<int ACT>  // 0 none, 1 leaky-relu(0.2), 2 tanh
__device__ __forceinline__ float actf(float v){
  if constexpr (ACT==1) return v>0.f ? v : 0.2f*v;
  else if constexpr (ACT==2) return 1.f - 2.f/(__expf(2.f*v)+1.f);
  else return v;
}

// stage a [64][64] f32 global matrix into a [64][LD] bf16 LDS tile (coalesced)
__device__ __forceinline__ void stage64(const float* __restrict__ G, unsigned short* L){
  const int t = threadIdx.x;
  #pragma unroll
  for(int j=0;j<4;j++){
    const int f4 = t + 256*j;
    const float4 v = reinterpret_cast<const float4*>(G)[f4];
    const int flat = f4*4;
    unsigned short* q = L + (flat>>6)*LD + (flat&63);
    q[0]=f2b(v.x); q[1]=f2b(v.y); q[2]=f2b(v.z); q[3]=f2b(v.w);
  }
}

// C = ACT(A @ W^T + bias).  A,W,C: [64][LD] bf16 LDS; bias: global f32 or null.
// thread t: rows i0=2*(t>>3), i0+1; cols (t&7)+8u  (stride-8 -> conflict-free b128 reads)
template<int ACT>
__device__ __noinline__ void mm_w(const unsigned short* A, const unsigned short* W,
                                  const float* __restrict__ bias, unsigned short* C){
  const int t=threadIdx.x, g=t&7, i0=(t>>3)*2;
  float acc0[8], acc1[8];
  #pragma unroll
  for(int u=0;u<8;u++){ const float b2 = bias ? bias[g+8*u] : 0.f; acc0[u]=b2; acc1[u]=b2; }
  #pragma unroll
  for(int k8=0;k8<8;k8++){
    float a0[8], a1[8];
    up8(A + i0*LD + k8*8, a0);
    up8(A + (i0+1)*LD + k8*8, a1);
    #pragma unroll
    for(int u=0;u<8;u++){
      float w[8]; up8(W + (g+8*u)*LD + k8*8, w);
      #pragma unroll
      for(int x=0;x<8;x++){ acc0[u]=fmaf(a0[x],w[x],acc0[u]); acc1[u]=fmaf(a1[x],w[x],acc1[u]); }
    }
  }
  #pragma unroll
  for(int u=0;u<8;u++){
    C[i0*LD + g+8*u]     = f2b(actf<ACT>(acc0[u]));
    C[(i0+1)*LD + g+8*u] = f2b(actf<ACT>(acc1[u]));
  }
}

// scores kept in registers: acc = A @ B^T  (same tiling as mm_w, no store)
__device__ __noinline__ void mm_score(const unsigned short* A, const unsigned short* Bm,
                                      float* acc0, float* acc1){
  const int t=threadIdx.x, g=t&7, i0=(t>>3)*2;
  #pragma unroll
  for(int u=0;u<8;u++){ acc0[u]=0.f; acc1[u]=0.f; }
  #pragma unroll
  for(int k8=0;k8<8;k8++){
    float a0[8], a1[8];
    up8(A + i0*LD + k8*8, a0);
    up8(A + (i0+1)*LD + k8*8, a1);
    #pragma unroll
    for(int u=0;u<8;u++){
      float w[8]; up8(Bm + (g+8*u)*LD + k8*8, w);
      #pragma unroll
      for(int x=0;x<8;x++){ acc0[u]=fmaf(a0[x],w[x],acc0[u]); acc1[u]=fmaf(a1[x],w[x],acc1[u]); }
    }
  }
}

// C = ACT(A @ B + bias)  (B in normal orientation).  cols (t&7)*8..+8 (consecutive)
template<int ACT>
__device__ __noinline__ void mm_n(const unsigned short* A, const unsigned short* Bm,
                                  const float* __restrict__ bias, unsigned short* C){
  const int t=threadIdx.x, g=t&7, i0=(t>>3)*2, h0=(t&7)*8;
  float acc0[8], acc1[8];
  #pragma unroll
  for(int x=0;x<8;x++){ const float b2 = bias ? bias[h0+x] : 0.f; acc0[x]=b2; acc1[x]=b2; }
  #pragma unroll
  for(int j8=0;j8<8;j8++){
    float a0[8], a1[8];
    up8(A + i0*LD + j8*8, a0);
    up8(A + (i0+1)*LD + j8*8, a1);
    #pragma unroll
    for(int y=0;y<8;y++){
      float bv8[8]; up8(Bm + (j8*8+y)*LD + h0, bv8);
      #pragma unroll
      for(int x=0;x<8;x++){ acc0[x]=fmaf(a0[y],bv8[x],acc0[x]); acc1[x]=fmaf(a1[y],bv8[x],acc1[x]); }
    }
  }
  #pragma unroll
  for(int x=0;x<8;x++){
    C[i0*LD + h0 + x]     = f2b(actf<ACT>(acc0[x]));
    C[(i0+1)*LD + h0 + x] = f2b(actf<ACT>(acc1[x]));
  }
  (void)g;
}

// softmax(s*SCALE) over the 64 cols spread across 8 lanes x 8 regs; write wgt (bf16)
__device__ __forceinline__ void softmax_plain(float* s0, float* s1, unsigned short* W){
  const int t=threadIdx.x, g=t&7, i0=(t>>3)*2;
  float mx0=s0[0], mx1=s1[0];
  #pragma unroll
  for(int u=1;u<8;u++){ mx0=fmaxf(mx0,s0[u]); mx1=fmaxf(mx1,s1[u]); }
  #pragma unroll
  for(int m=1;m<8;m<<=1){ mx0=fmaxf(mx0,__shfl_xor(mx0,m)); mx1=fmaxf(mx1,__shfl_xor(mx1,m)); }
  float d0=0.f, d1=0.f;
  #pragma unroll
  for(int u=0;u<8;u++){
    s0[u]=__expf((s0[u]-mx0)*SCALE); d0+=s0[u];
    s1[u]=__expf((s1[u]-mx1)*SCALE); d1+=s1[u];
  }
  #pragma unroll
  for(int m=1;m<8;m<<=1){ d0+=__shfl_xor(d0,m); d1+=__shfl_xor(d1,m); }
  const float r0=1.f/d0, r1=1.f/d1;
  #pragma unroll
  for(int u=0;u<8;u++){
    W[i0*LD + g+8*u]     = f2b(s0[u]*r0);
    W[(i0+1)*LD + g+8*u] = f2b(s1[u]*r1);
  }
}

// consensus softmax: s = (mask*dot + qq.bk)*SCALE; wgt = softmax(s)*mask  (masked
// entries keep their exp(qb*SCALE) contribution in the denominator, per reference)
__device__ __noinline__ void softmax_cons(float* s0, float* s1, const unsigned short* QQ,
                                          const float* __restrict__ bk, int inv,
                                          unsigned short* W, const float* rnd_s,
                                          const float* a_s){
  const int t=threadIdx.x, g=t&7, i0=(t>>3)*2;
  // qb = dot(qq_row, bk) via 8-lane partial + shfl reduce
  float q0[8], q1[8];
  up8(QQ + i0*LD + g*8, q0);
  up8(QQ + (i0+1)*LD + g*8, q1);
  float pb0=0.f, pb1=0.f;
  #pragma unroll
  for(int x=0;x<8;x++){ const float w=bk[g*8+x]; pb0=fmaf(q0[x],w,pb0); pb1=fmaf(q1[x],w,pb1); }
  #pragma unroll
  for(int m=1;m<8;m<<=1){ pb0+=__shfl_xor(pb0,m); pb1+=__shfl_xor(pb1,m); }

  const float ai0=a_s[i0], ai1=a_s[i0+1];
  const bool gi0 = rnd_s[i0]  > ai0;
  const bool gi1 = rnd_s[i0+1]> ai1;
  float mk0[8], mk1[8];
  #pragma unroll
  for(int u=0;u<8;u++){
    const float rj = rnd_s[g+8*u];
    float m0 = (gi0 || rj>ai0) ? 1.f : 0.f;
    float m1 = (gi1 || rj>ai1) ? 1.f : 0.f;
    if(inv){ m0=1.f-m0; m1=1.f-m1; }
    mk0[u]=m0; mk1[u]=m1;
    s0[u] = (m0*s0[u]+pb0)*SCALE;
    s1[u] = (m1*s1[u]+pb1)*SCALE;
  }
  float mx0=s0[0], mx1=s1[0];
  #pragma unroll
  for(int u=1;u<8;u++){ mx0=fmaxf(mx0,s0[u]); mx1=fmaxf(mx1,s1[u]); }
  #pragma unroll
  for(int m=1;m<8;m<<=1){ mx0=fmaxf(mx0,__shfl_xor(mx0,m)); mx1=fmaxf(mx1,__shfl_xor(mx1,m)); }
  float d0=0.f, d1=0.f;
  #pragma unroll
  for(int u=0;u<8;u++){
    s0[u]=__expf(s0[u]-mx0); d0+=s0[u];
    s1[u]=__expf(s1[u]-mx1); d1+=s1[u];
  }
  #pragma unroll
  for(int m=1;m<8;m<<=1){ d0+=__shfl_xor(d0,m); d1+=__shfl_xor(d1,m); }
  const float r0=1.f/d0, r1=1.f/d1;
  #pragma unroll
  for(int u=0;u<8;u++){
    W[i0*LD + g+8*u]     = f2b(s0[u]*r0*mk0[u]);
    W[(i0+1)*LD + g+8*u] = f2b(s1[u]*r1*mk1[u]);
  }
}

__device__ __forceinline__ void epilogue(const unsigned short* O1, const unsigned short* O2,
                                         const float* Sf, const Params& p){
  const int t=threadIdx.x, i=t>>2, a0=t&3, a1=(t&3)+4;
  float am0=p.mean_b[a0], am1=p.mean_b[a1];
  float al0=p.ls_b[a0],   al1=p.ls_b[a1];
  const float* mw = Sf;            // [8][132]
  const float* lw = Sf + 1056;     // [8][132]
  #pragma unroll
  for(int k8=0;k8<8;k8++){
    float o[8]; up8(O1 + i*LD + k8*8, o);
    #pragma unroll
    for(int x=0;x<8;x++){
      const float v = o[x]>0.f ? o[x] : 0.2f*o[x];
      const int d = k8*8+x;
      am0=fmaf(v,mw[a0*132+d],am0); am1=fmaf(v,mw[a1*132+d],am1);
      al0=fmaf(v,lw[a0*132+d],al0); al1=fmaf(v,lw[a1*132+d],al1);
    }
  }
  #pragma unroll
  for(int k8=0;k8<8;k8++){
    float o[8]; up8(O2 + i*LD + k8*8, o);
    #pragma unroll
    for(int x=0;x<8;x++){
      const float v = o[x]>0.f ? o[x] : 0.2f*o[x];
      const int d = 64 + k8*8+x;
      am0=fmaf(v,mw[a0*132+d],am0); am1=fmaf(v,mw[a1*132+d],am1);
      al0=fmaf(v,lw[a0*132+d],al0); al1=fmaf(v,lw[a1*132+d],al1);
    }
  }
  const int base = (blockIdx.x*NN + i)*8;
  p.out[base+a0]=am0; p.out[base+a1]=am1;
  const float l0=fminf(fmaxf(al0,-20.f),2.f);
  const float l1=fminf(fmaxf(al1,-20.f),2.f);
  p.out[p.std_off+base+a0]=__expf(l0);
  p.out[p.std_off+base+a1]=__expf(l1);
}

__global__ __launch_bounds__(256,2) void rap_kernel(Params p){
  __shared__ __align__(16) unsigned short Buf[5][NN*LD];  // 5 x 9216 B
  __shared__ __align__(16) unsigned short Wst[NN*LD];     // staging (also f32 epilogue wts)
  __shared__ float rnd_s[NN];
  __shared__ float a_s[NN];
  const int b = blockIdx.x, t = threadIdx.x;

  if(t < NN){
    rnd_s[t] = p.rnd[b*NN+t];
    const int iv = p.idx[b*NN+t];
    a_s[t] = p.rnd[b*NN+iv];
  }
  // stage x[b] -> Buf0 (bf16)
  {
    const float* G = p.x + (size_t)b*4096;
    #pragma unroll
    for(int j=0;j<4;j++){
      const int f4 = t + 256*j;
      const float4 v = reinterpret_cast<const float4*>(G)[f4];
      const int flat = f4*4;
      unsigned short* q = Buf[0] + (flat>>6)*LD + (flat&63);
      q[0]=f2b(v.x); q[1]=f2b(v.y); q[2]=f2b(v.z); q[3]=f2b(v.w);
    }
  }
  stage64(p.embed_w, Wst);
  __syncthreads();
  mm_w<1>(Buf[0], Wst, p.embed_b, Buf[1]);                 // E
  __syncthreads();
  stage64(p.ia_wq, Wst); __syncthreads();
  mm_w<0>(Buf[1], Wst, p.ia_bq, Buf[0]);                   // Q
  __syncthreads();
  stage64(p.ia_wk, Wst); __syncthreads();
  mm_w<0>(Buf[1], Wst, p.ia_bk, Buf[2]);                   // K
  __syncthreads();
  stage64(p.ia_wv, Wst); __syncthreads();
  mm_w<0>(Buf[1], Wst, p.ia_bv, Buf[4]);                   // V
  __syncthreads();
  {
    float s0[8], s1[8];
    mm_score(Buf[0], Buf[2], s0, s1);                      // Q K^T
    __syncthreads();
    softmax_plain(s0, s1, Buf[0]);                         // WGT over Q
  }
  __syncthreads();
  mm_n<0>(Buf[0], Buf[4], nullptr, Buf[2]);                // P = WGT @ V  (over K)
  __syncthreads();
  stage64(p.ia_wo, Wst); __syncthreads();
  mm_w<2>(Buf[2], Wst, p.ia_bo, Buf[1]);                   // ATT = tanh(.) (over E)
  __syncthreads();
  stage64(p.msg_w, Wst); __syncthreads();
  mm_w<0>(Buf[1], Wst, p.msg_b, Buf[0]);                   // MSG
  __syncthreads();
  stage64(p.st_w, Wst); __syncthreads();
  mm_w<0>(Buf[1], Wst, p.st_b, Buf[2]);                    // TEMP
  __syncthreads();
  // ---- consensus 1 (mask = mg) ----
  stage64(p.c1_wq, Wst); __syncthreads();
  mm_w<0>(Buf[2], Wst, p.c1_bq, Buf[3]);                   // QQ1
  __syncthreads();
  stage64(p.c1_wk, Wst); __syncthreads();
  mm_w<0>(Buf[0], Wst, nullptr, Buf[4]);                   // KM1 (no bias)
  __syncthreads();
  stage64(p.c1_wv, Wst); __syncthreads();
  mm_w<0>(Buf[0], Wst, nullptr, Buf[1]);                   // VM1 (no bias)
  __syncthreads();
  {
    float s0[8], s1[8];
    mm_score(Buf[3], Buf[4], s0, s1);                      // QQ1 KM1^T
    __syncthreads();
    softmax_cons(s0, s1, Buf[3], p.c1_bk, 0, Buf[4], rnd_s, a_s); // WGT1*mg over KM1
  }
  __syncthreads();
  mm_n<0>(Buf[4], Buf[1], p.c1_bv, Buf[3]);                // CTX1 (+bv) over QQ1
  __syncthreads();
  stage64(p.c1_wo, Wst); __syncthreads();
  mm_w<0>(Buf[3], Wst, p.c1_bo, Buf[4]);                   // O1 over WGT1
  __syncthreads();
  // ---- consensus 2 (mask = 1-mg) ----
  stage64(p.c2_wq, Wst); __syncthreads();
  mm_w<0>(Buf[2], Wst, p.c2_bq, Buf[1]);                   // QQ2 (over VM1)
  __syncthreads();
  stage64(p.c2_wk, Wst); __syncthreads();
  mm_w<0>(Buf[0], Wst, nullptr, Buf[3]);                   // KM2 (over CTX1)
  __syncthreads();
  stage64(p.c2_wv, Wst); __syncthreads();
  mm_w<0>(Buf[0], Wst, nullptr, Buf[2]);                   // VM2 (over TEMP)
  __syncthreads();
  {
    float s0[8], s1[8];
    mm_score(Buf[1], Buf[3], s0, s1);                      // QQ2 KM2^T
    __syncthreads();
    softmax_cons(s0, s1, Buf[1], p.c2_bk, 1, Buf[3], rnd_s, a_s); // WGT2*ml over KM2
  }
  __syncthreads();
  mm_n<0>(Buf[3], Buf[2], p.c2_bv, Buf[0]);                // CTX2 (+bv) over MSG
  __syncthreads();
  stage64(p.c2_wo, Wst); __syncthreads();
  mm_w<0>(Buf[0], Wst, p.c2_bo, Buf[3]);                   // O2 over WGT2
  __syncthreads();
  // ---- epilogue: stage mean/ls weights (f32) into Wst, then heads ----
  {
    float* Sf = reinterpret_cast<float*>(Wst);
    #pragma unroll
    for(int j=0;j<4;j++){
      const int f = t + 256*j;            // 0..1023
      const int a = f>>7, k = f&127;
      Sf[a*132+k]        = p.mean_w[f];
      Sf[1056 + a*132+k] = p.ls_w[f];
    }
  }
  __syncthreads();
  epilogue(Buf[4], Buf[3], reinterpret_cast<const float*>(Wst), p);
}

} // namespace

extern "C" void kernel_launch(void* const* d_in, const int* in_sizes, int n_in,
                              void* d_out, int out_size, void* d_ws, size_t ws_size,
                              hipStream_t stream){
  (void)n_in; (void)out_size; (void)d_ws; (void)ws_size;
  Params p;
  p.x       = (const float*)d_in[0];
  p.rnd     = (const float*)d_in[1];
  p.idx     = (const int*)  d_in[2];
  p.embed_w = (const float*)d_in[3];  p.embed_b = (const float*)d_in[4];
  p.ia_wq = (const float*)d_in[5];  p.ia_bq = (const float*)d_in[6];
  p.ia_wk = (const float*)d_in[7];  p.ia_bk = (const float*)d_in[8];
  p.ia_wv = (const float*)d_in[9];  p.ia_bv = (const float*)d_in[10];
  p.ia_wo = (const float*)d_in[11]; p.ia_bo = (const float*)d_in[12];
  p.c1_wq = (const float*)d_in[13]; p.c1_bq = (const float*)d_in[14];
  p.c1_wk = (const float*)d_in[15]; p.c1_bk = (const float*)d_in[16];
  p.c1_wv = (const float*)d_in[17]; p.c1_bv = (const float*)d_in[18];
  p.c1_wo = (const float*)d_in[19]; p.c1_bo = (const float*)d_in[20];
  p.c2_wq = (const float*)d_in[21]; p.c2_bq = (const float*)d_in[22];
  p.c2_wk = (const float*)d_in[23]; p.c2_bk = (const float*)d_in[24];
  p.c2_wv = (const float*)d_in[25]; p.c2_bv = (const float*)d_in[26];
  p.c2_wo = (const float*)d_in[27]; p.c2_bo = (const float*)d_in[28];
  p.msg_w = (const float*)d_in[29]; p.msg_b = (const float*)d_in[30];
  p.st_w  = (const float*)d_in[31]; p.st_b  = (const float*)d_in[32];
  p.mean_w= (const float*)d_in[33]; p.mean_b= (const float*)d_in[34];
  p.ls_w  = (const float*)d_in[35]; p.ls_b  = (const float*)d_in[36];
  p.out = (float*)d_out;
  const int Bb = in_sizes[0] / 4096;   // B (x is [B,64,64])
  p.std_off = Bb * 64 * 8;
  rap_kernel<<<dim3(Bb), dim3(256), 0, stream>>>(p);
}

// Round 2
// 149.571 us; speedup vs baseline: 26.5534x; 26.5534x over previous
//
#include <hip/hip_runtime.h>

namespace {

typedef __bf16 bf16x8 __attribute__((ext_vector_type(8)));
typedef float f32x4 __attribute__((ext_vector_type(4)));
typedef unsigned int uint4v __attribute__((ext_vector_type(4)));

#define MFMA16(a,b,c) __builtin_amdgcn_mfma_f32_16x16x32_bf16((a),(b),(c),0,0,0)

constexpr float SCALE = 0.125f;   // 1/sqrt(64)

struct Params {
  const float *x, *rnd; const int *idx;
  const float *embed_w, *embed_b;
  const float *ia_wq, *ia_bq, *ia_wk, *ia_bk, *ia_wv, *ia_bv, *ia_wo, *ia_bo;
  const float *c1_wq, *c1_bq, *c1_wk, *c1_bk, *c1_wv, *c1_bv, *c1_wo, *c1_bo;
  const float *c2_wq, *c2_bq, *c2_wk, *c2_bk, *c2_wv, *c2_bv, *c2_wo, *c2_bo;
  const float *msg_w, *msg_b, *st_w, *st_b;
  const float *mean_w, *mean_b, *ls_w, *ls_b;
  float *out; int std_off;
};

__device__ __forceinline__ unsigned asu(float f){ union{unsigned u;float f;} c; c.f=f; return c.u; }
__device__ __forceinline__ unsigned short f2b(float f){
  unsigned u = asu(f);
  u += 0x7fffu + ((u>>16)&1u);          // round-to-nearest-even bf16
  return (unsigned short)(u>>16);
}
__device__ __forceinline__ unsigned pack2(float a, float b){
  return (unsigned)f2b(a) | ((unsigned)f2b(b)<<16);
}

template<int ACT>  // 0 none, 1 leaky-relu(0.2), 2 tanh
__device__ __forceinline__ float actf(float v){
  if constexpr (ACT==1) return v>0.f ? v : 0.2f*v;
  else if constexpr (ACT==2) return 1.f - 2.f/(__expf(2.f*v)+1.f);
  else return v;
}

// Swizzled 64x64 bf16 tile: byte(row, colbyte) = row*128 + (colbyte ^ ((row&7)<<4))
// Fragment read: 16B = 8 contiguous-k bf16 (A: row=lane&15 of tile; B: row of B^T-source)
__device__ __forceinline__ bf16x8 fragld(const char* buf, int row, int kb){
  const int byte = row*128 + (kb ^ ((row&7)<<4));
  return __builtin_bit_cast(bf16x8, *reinterpret_cast<const uint4v*>(buf + byte));
}

// stage a [64][64] f32 global matrix -> swizzled bf16 LDS tile (coalesced float4 loads)
__device__ __forceinline__ void stageM(const float* __restrict__ G, char* L){
  const int t = threadIdx.x;
  #pragma unroll
  for(int j=0;j<4;j++){
    const int f4 = t + 256*j;               // 0..1023
    const float4 v = reinterpret_cast<const float4*>(G)[f4];
    const int row = f4 >> 4;                // 0..63
    const int col = (f4 & 15) * 4;          // 0..60
    uint2 pk; pk.x = pack2(v.x, v.y); pk.y = pack2(v.z, v.w);
    const int byte = row*128 + ((2*col) ^ ((row&7)<<4));
    *reinterpret_cast<uint2*>(L + byte) = pk;
  }
}

// stage combined head weights [16][128] bf16: rows 0-7 = mean_w, 8-15 = ls_w (stride 256B)
__device__ __forceinline__ void stageHW(const float* __restrict__ MW,
                                        const float* __restrict__ LW, char* L){
  const int t = threadIdx.x;
  const int row = t >> 4, col = (t & 15) * 8;
  const float* src = (row < 8) ? (MW + row*128 + col) : (LW + (row-8)*128 + col);
  const float4 v0 = reinterpret_cast<const float4*>(src)[0];
  const float4 v1 = reinterpret_cast<const float4*>(src)[1];
  uint4 pk; pk.x=pack2(v0.x,v0.y); pk.y=pack2(v0.z,v0.w);
  pk.z=pack2(v1.x,v1.y); pk.w=pack2(v1.z,v1.w);
  const int byte = row*256 + ((2*col) ^ ((row&7)<<4));
  *reinterpret_cast<uint4*>(L + byte) = pk;
}

// C = ACT(A @ Bt^T + bias).  A: swizzled tile (wave reads own 16 rows as A-frags);
// Bt: swizzled tile read row-wise as B-frags (weight W, or K, or transposed-stored V).
// TST: store result transposed (for V/VM buffers). QB: also emit qb[row]=row.(bkw).
template<int ACT, bool TST, bool QB>
__device__ __forceinline__ void mm_core(const char* A, const char* Bt,
                                        const float* __restrict__ bias, char* C,
                                        const float* __restrict__ bkw, float* qbdst){
  const int t = threadIdx.x, fr = t & 15, fg = (t>>4)&3, wv = t>>6;
  f32x4 acc[4];
  #pragma unroll
  for(int n=0;n<4;n++) acc[n] = f32x4{0.f,0.f,0.f,0.f};
  const bf16x8 a0 = fragld(A, 16*wv+fr, fg*16);
  const bf16x8 a1 = fragld(A, 16*wv+fr, 64 + fg*16);
  #pragma unroll
  for(int n=0;n<4;n++){
    acc[n] = MFMA16(a0, fragld(Bt, n*16+fr, fg*16), acc[n]);
    acc[n] = MFMA16(a1, fragld(Bt, n*16+fr, 64 + fg*16), acc[n]);
  }
  float bz[4];
  #pragma unroll
  for(int n=0;n<4;n++) bz[n] = bias ? bias[n*16+fr] : 0.f;
  if constexpr (QB){
    float qp[4] = {0.f,0.f,0.f,0.f};
    #pragma unroll
    for(int n=0;n<4;n++){
      const float bkv = bkw[n*16+fr];
      #pragma unroll
      for(int r=0;r<4;r++) qp[r] = fmaf(acc[n][r]+bz[n], bkv, qp[r]);
    }
    #pragma unroll
    for(int m=1;m<16;m<<=1){
      #pragma unroll
      for(int r=0;r<4;r++) qp[r] += __shfl_xor(qp[r], m);
    }
    if(fr==0){
      #pragma unroll
      for(int r=0;r<4;r++) qbdst[16*wv + 4*fg + r] = qp[r];
    }
  }
  if constexpr (!TST){
    #pragma unroll
    for(int n=0;n<4;n++){
      #pragma unroll
      for(int r=0;r<4;r++){
        const int R = 16*wv + 4*fg + r;
        const int byte = R*128 + ((2*(n*16+fr)) ^ ((R&7)<<4));
        *reinterpret_cast<unsigned short*>(C + byte) = f2b(actf<ACT>(acc[n][r] + bz[n]));
      }
    }
  } else {
    // transposed store: value (R,c) -> buffer row c, col R; 4 rows pack into one b64
    #pragma unroll
    for(int n=0;n<4;n++){
      const int c = n*16 + fr;
      uint2 pk;
      pk.x = pack2(actf<ACT>(acc[n][0]+bz[n]), actf<ACT>(acc[n][1]+bz[n]));
      pk.y = pack2(actf<ACT>(acc[n][2]+bz[n]), actf<ACT>(acc[n][3]+bz[n]));
      const int byte = c*128 + ((2*(16*wv + 4*fg)) ^ ((c&7)<<4));
      *reinterpret_cast<uint2*>(C + byte) = pk;
    }
  }
}

// MODE 0: P = softmax(Aq@Bk^T * SCALE).  MODE 1/2: consensus softmax with mask
// mg (1) or 1-mg (2): s=(m*dot+qb)*SCALE, P = softmax(s)*m.  P written in-place-safe.
template<int MODE>
__device__ __forceinline__ void score_softmax(const char* Aq, const char* Bk, char* P,
                                              const float* rs, const float* as_,
                                              const float* qb){
  const int t = threadIdx.x, fr = t & 15, fg = (t>>4)&3, wv = t>>6;
  f32x4 acc[4];
  #pragma unroll
  for(int n=0;n<4;n++) acc[n] = f32x4{0.f,0.f,0.f,0.f};
  const bf16x8 a0 = fragld(Aq, 16*wv+fr, fg*16);
  const bf16x8 a1 = fragld(Aq, 16*wv+fr, 64 + fg*16);
  #pragma unroll
  for(int n=0;n<4;n++){
    acc[n] = MFMA16(a0, fragld(Bk, n*16+fr, fg*16), acc[n]);
    acc[n] = MFMA16(a1, fragld(Bk, n*16+fr, 64 + fg*16), acc[n]);
  }
  float rc[4], aR[4], giR[4], qR[4];
  if constexpr (MODE != 0){
    #pragma unroll
    for(int n=0;n<4;n++) rc[n] = rs[n*16+fr];
    #pragma unroll
    for(int r=0;r<4;r++){
      const int R = 16*wv + 4*fg + r;
      aR[r] = as_[R];
      giR[r] = (rs[R] > aR[r]) ? 1.f : 0.f;
      qR[r] = qb[R];
    }
    #pragma unroll
    for(int n=0;n<4;n++){
      #pragma unroll
      for(int r=0;r<4;r++){
        float mv = (giR[r] != 0.f || rc[n] > aR[r]) ? 1.f : 0.f;
        if constexpr (MODE==2) mv = 1.f - mv;
        acc[n][r] = (mv*acc[n][r] + qR[r])*SCALE;
      }
    }
  }
  float mx[4];
  #pragma unroll
  for(int r=0;r<4;r++)
    mx[r] = fmaxf(fmaxf(acc[0][r],acc[1][r]), fmaxf(acc[2][r],acc[3][r]));
  #pragma unroll
  for(int m=1;m<16;m<<=1){
    #pragma unroll
    for(int r=0;r<4;r++) mx[r] = fmaxf(mx[r], __shfl_xor(mx[r], m));
  }
  float sm[4] = {0.f,0.f,0.f,0.f};
  #pragma unroll
  for(int n=0;n<4;n++){
    #pragma unroll
    for(int r=0;r<4;r++){
      const float e = __expf(MODE==0 ? (acc[n][r]-mx[r])*SCALE : (acc[n][r]-mx[r]));
      acc[n][r] = e; sm[r] += e;
    }
  }
  #pragma unroll
  for(int m=1;m<16;m<<=1){
    #pragma unroll
    for(int r=0;r<4;r++) sm[r] += __shfl_xor(sm[r], m);
  }
  float ri[4];
  #pragma unroll
  for(int r=0;r<4;r++) ri[r] = 1.f/sm[r];
  #pragma unroll
  for(int n=0;n<4;n++){
    #pragma unroll
    for(int r=0;r<4;r++){
      float val = acc[n][r]*ri[r];
      if constexpr (MODE != 0){
        float mv = (giR[r] != 0.f || rc[n] > aR[r]) ? 1.f : 0.f;
        if constexpr (MODE==2) mv = 1.f - mv;
        val *= mv;
      }
      const int R = 16*wv + 4*fg + r;
      const int byte = R*128 + ((2*(n*16+fr)) ^ ((R&7)<<4));
      *reinterpret_cast<unsigned short*>(P + byte) = f2b(val);
    }
  }
}

// out[:, :8] = lrelu([O1|O2]) @ mean_w^T + mean_b ; std = exp(clip(.. @ ls_w^T + ls_b))
__device__ __forceinline__ void heads(const char* O1, const char* O2, const char* HW,
                                      const Params& p, int b){
  const int t = threadIdx.x, fr = t & 15, fg = (t>>4)&3, wv = t>>6;
  f32x4 acc = {0.f,0.f,0.f,0.f};
  #pragma unroll
  for(int kt=0;kt<4;kt++){
    const bf16x8 af = fragld(kt<2 ? O1 : O2, 16*wv+fr, (kt&1)*64 + fg*16);
    const int byte = fr*256 + (((kt*64) + fg*16) ^ ((fr&7)<<4));
    const bf16x8 bf_ = __builtin_bit_cast(bf16x8, *reinterpret_cast<const uint4v*>(HW + byte));
    acc = MFMA16(af, bf_, acc);
  }
  const float bz = (fr < 8) ? p.mean_b[fr] : p.ls_b[fr-8];
  #pragma unroll
  for(int r=0;r<4;r++){
    const int R = 16*wv + 4*fg + r;
    const int g = (b*64 + R)*8;
    float v = acc[r] + bz;
    if(fr < 8){
      p.out[g + fr] = v;
    } else {
      v = fminf(fmaxf(v, -20.f), 2.f);
      p.out[p.std_off + g + (fr-8)] = __expf(v);
    }
  }
}

#define BAR() __syncthreads()

__global__ __launch_bounds__(256,3) void rap_kernel(Params p){
  __shared__ __align__(16) char B0[8192];
  __shared__ __align__(16) char B1[8192];
  __shared__ __align__(16) char B2[8192];
  __shared__ __align__(16) char B3[8192];
  __shared__ __align__(16) char B4[8192];
  __shared__ __align__(16) char WS[8192];
  __shared__ float rnd_s[64], a_s[64], qb1_s[64], qb2_s[64];
  const int b = blockIdx.x, t = threadIdx.x;

  if(t < 64){
    rnd_s[t] = p.rnd[b*64 + t];
    a_s[t]   = p.rnd[b*64 + p.idx[b*64 + t]];
  }
  stageM(p.x + (size_t)b*4096, B0);
  stageM(p.embed_w, WS);
  BAR();
  mm_core<1,false,false>(B0, WS, p.embed_b, B1, nullptr, nullptr);   // E (lrelu)
  BAR(); stageM(p.ia_wq, WS); BAR();
  mm_core<0,false,false>(B1, WS, p.ia_bq, B0, nullptr, nullptr);     // Q
  BAR(); stageM(p.ia_wk, WS); BAR();
  mm_core<0,false,false>(B1, WS, p.ia_bk, B2, nullptr, nullptr);     // K
  BAR(); stageM(p.ia_wv, WS); BAR();
  mm_core<0,true ,false>(B1, WS, p.ia_bv, B4, nullptr, nullptr);     // V^T
  BAR();
  score_softmax<0>(B0, B2, B0, rnd_s, a_s, nullptr);                 // P (in-place over Q)
  BAR();
  mm_core<0,false,false>(B0, B4, nullptr, B2, nullptr, nullptr);     // ATT0 = P@V (over K)
  BAR(); stageM(p.ia_wo, WS); BAR();
  mm_core<2,false,false>(B2, WS, p.ia_bo, B1, nullptr, nullptr);     // ATT = tanh (over E)
  BAR(); stageM(p.msg_w, WS); BAR();
  mm_core<0,false,false>(B1, WS, p.msg_b, B0, nullptr, nullptr);     // MSG (over P)
  BAR(); stageM(p.st_w, WS); BAR();
  mm_core<0,false,false>(B1, WS, p.st_b, B2, nullptr, nullptr);      // TEMP (over ATT0)
  BAR(); stageM(p.c1_wq, WS); BAR();
  mm_core<0,false,true >(B2, WS, p.c1_bq, B3, p.c1_bk, qb1_s);       // QQ1 + qb1
  BAR(); stageM(p.c2_wq, WS); BAR();
  mm_core<0,false,true >(B2, WS, p.c2_bq, B2, p.c2_bk, qb2_s);       // QQ2 (in-place) + qb2
  BAR(); stageM(p.c1_wk, WS); BAR();
  mm_core<0,false,false>(B0, WS, nullptr, B1, nullptr, nullptr);     // KM1 (over ATT)
  BAR(); stageM(p.c1_wv, WS); BAR();
  mm_core<0,true ,false>(B0, WS, nullptr, B4, nullptr, nullptr);     // VM1^T (over V)
  BAR();
  score_softmax<1>(B3, B1, B3, rnd_s, a_s, qb1_s);                   // P1 (in-place)
  BAR();
  mm_core<0,false,false>(B3, B4, p.c1_bv, B1, nullptr, nullptr);     // CTX1 (over KM1)
  BAR(); stageM(p.c1_wo, WS); BAR();
  mm_core<1,false,false>(B1, WS, p.c1_bo, B3, nullptr, nullptr);     // O1 lrelu (over P1)
  BAR(); stageM(p.c2_wk, WS); BAR();
  mm_core<0,false,false>(B0, WS, nullptr, B1, nullptr, nullptr);     // KM2 (over CTX1)
  BAR(); stageM(p.c2_wv, WS); BAR();
  mm_core<0,true ,false>(B0, WS, nullptr, B4, nullptr, nullptr);     // VM2^T (over VM1)
  BAR();
  score_softmax<2>(B2, B1, B2, rnd_s, a_s, qb2_s);                   // P2 (in-place)
  BAR();
  mm_core<0,false,false>(B2, B4, p.c2_bv, B0, nullptr, nullptr);     // CTX2 (over MSG)
  BAR(); stageM(p.c2_wo, WS); BAR();
  mm_core<1,false,false>(B0, WS, p.c2_bo, B2, nullptr, nullptr);     // O2 lrelu (over P2)
  BAR();
  stageHW(p.mean_w, p.ls_w, WS);
  BAR();
  heads(B3, B2, WS, p, b);
}

} // namespace

extern "C" void kernel_launch(void* const* d_in, const int* in_sizes, int n_in,
                              void* d_out, int out_size, void* d_ws, size_t ws_size,
                              hipStream_t stream){
  (void)n_in; (void)out_size; (void)d_ws; (void)ws_size;
  Params p;
  p.x       = (const float*)d_in[0];
  p.rnd     = (const float*)d_in[1];
  p.idx     = (const int*)  d_in[2];
  p.embed_w = (const float*)d_in[3];  p.embed_b = (const float*)d_in[4];
  p.ia_wq = (const float*)d_in[5];  p.ia_bq = (const float*)d_in[6];
  p.ia_wk = (const float*)d_in[7];  p.ia_bk = (const float*)d_in[8];
  p.ia_wv = (const float*)d_in[9];  p.ia_bv = (const float*)d_in[10];
  p.ia_wo = (const float*)d_in[11]; p.ia_bo = (const float*)d_in[12];
  p.c1_wq = (const float*)d_in[13]; p.c1_bq = (const float*)d_in[14];
  p.c1_wk = (const float*)d_in[15]; p.c1_bk = (const float*)d_in[16];
  p.c1_wv = (const float*)d_in[17]; p.c1_bv = (const float*)d_in[18];
  p.c1_wo = (const float*)d_in[19]; p.c1_bo = (const float*)d_in[20];
  p.c2_wq = (const float*)d_in[21]; p.c2_bq = (const float*)d_in[22];
  p.c2_wk = (const float*)d_in[23]; p.c2_bk = (const float*)d_in[24];
  p.c2_wv = (const float*)d_in[25]; p.c2_bv = (const float*)d_in[26];
  p.c2_wo = (const float*)d_in[27]; p.c2_bo = (const float*)d_in[28];
  p.msg_w = (const float*)d_in[29]; p.msg_b = (const float*)d_in[30];
  p.st_w  = (const float*)d_in[31]; p.st_b  = (const float*)d_in[32];
  p.mean_w= (const float*)d_in[33]; p.mean_b= (const float*)d_in[34];
  p.ls_w  = (const float*)d_in[35]; p.ls_b  = (const float*)d_in[36];
  p.out = (float*)d_out;
  const int Bb = in_sizes[0] / 4096;   // x is [B,64,64]
  p.std_off = Bb * 64 * 8;
  rap_kernel<<<dim3(Bb), dim3(256), 0, stream>>>(p);
}

// Round 3
// 136.218 us; speedup vs baseline: 29.1562x; 1.0980x over previous
//
#include <hip/hip_runtime.h>

namespace {

typedef __bf16 bf16x8 __attribute__((ext_vector_type(8)));
typedef float f32x4 __attribute__((ext_vector_type(4)));
typedef unsigned int uint4v __attribute__((ext_vector_type(4)));

#define MFMA16(a,b,c) __builtin_amdgcn_mfma_f32_16x16x32_bf16((a),(b),(c),0,0,0)

constexpr float SCALE = 0.125f;   // 1/sqrt(64)

// ---------------- ws layout ----------------
// slot s in [0,13): pre-swizzled bf16 64x64 weight tile, 8192 B each.
//   order: 0 embed, 1 ia_wq, 2 ia_wk, 3 ia_wv, 4 ia_wo, 5 F_qq1, 6 F_km1,
//          7 F_vm1, 8 c1_wo, 9 F_qq2, 10 F_vm2, 11 F_km2, 12 c2_wo
// offset 13*8192: head weights [16][128] bf16 pre-swizzled, 4096 B
// offset 110592: fused biases f32: 6 x 64 (qq1, km1, vm1, qq2, vm2, km2)
constexpr int WS_HEAD = 13*8192;
constexpr int WS_BIAS = WS_HEAD + 4096;

struct PrepParams {
  const float* plain_src[7];
  int          plain_slot[7];
  const float* fuse_A[6];
  const float* fuse_B[6];
  const float* fuse_b[6];
  const float* fuse_extra[6];
  int          fuse_slot[6];
  const float* mean_w; const float* ls_w;
  char* ws;
};

// Pre-swizzle rule (element space): dst[r*64 + e] = src[r][ e ^ ((r&7)<<3) ]
// so that a LINEAR global_load_lds write yields the XOR-swizzled LDS tile
// (byte swizzle: colbyte ^ ((row&7)<<4)).
__global__ void prep_kernel(PrepParams q){
  const int job = blockIdx.x, t = threadIdx.x;
  __bf16* W16 = reinterpret_cast<__bf16*>(q.ws);
  if(job < 7){
    const float* __restrict__ src = q.plain_src[job];
    __bf16* dst = W16 + q.plain_slot[job]*4096;
    #pragma unroll
    for(int i=0;i<16;i++){
      const int idx = t*16+i, r = idx>>6, e = idx&63;
      dst[idx] = (__bf16)src[r*64 + (e ^ ((r&7)<<3))];
    }
  } else if(job < 13){
    const int fj = job-7;
    const float* __restrict__ A  = q.fuse_A[fj];
    const float* __restrict__ Bs = q.fuse_B[fj];
    const float* __restrict__ bs = q.fuse_b[fj];
    const float* __restrict__ ex = q.fuse_extra[fj];
    __bf16* dst = W16 + q.fuse_slot[fj]*4096;
    float* bdst = reinterpret_cast<float*>(q.ws + WS_BIAS) + fj*64;
    const int r = t>>2, c0 = (t&3)*16;
    float acc[16];
    #pragma unroll
    for(int j=0;j<16;j++) acc[j]=0.f;
    for(int k=0;k<64;k++){
      const float a = A[r*64+k];
      #pragma unroll
      for(int j=0;j<16;j++) acc[j] = fmaf(a, Bs[k*64+c0+j], acc[j]);
    }
    #pragma unroll
    for(int j=0;j<16;j++){
      const int c = c0+j;
      dst[r*64 + (c ^ ((r&7)<<3))] = (__bf16)acc[j];
    }
    if(t < 64){
      float b = ex ? ex[t] : 0.f;
      for(int k=0;k<64;k++) b = fmaf(A[t*64+k], bs[k], b);
      bdst[t] = b;
    }
  } else {
    // head weights: rows 0-7 mean_w, 8-15 ls_w, 128 cols, row stride 256 B
    __bf16* dst = W16 + WS_HEAD/2;
    #pragma unroll
    for(int i=0;i<8;i++){
      const int flat = t*8+i, row = flat>>7, e = flat&127;
      const int col = e ^ ((row&7)<<3);
      const float v = (row<8) ? q.mean_w[row*128+col] : q.ls_w[(row-8)*128+col];
      dst[flat] = (__bf16)v;
    }
  }
}

// ---------------- main kernel ----------------
struct Params {
  const float *x, *rnd; const int *idx;
  const float *embed_b, *ia_bq, *ia_bk, *ia_bv, *ia_bo;
  const float *c1_bk, *c1_bv, *c1_bo, *c2_bk, *c2_bv, *c2_bo;
  const float *mean_b, *ls_b;
  const char* ws;
  float* out; int std_off;
};

__device__ __forceinline__ unsigned short f2b(float f){
  return __builtin_bit_cast(unsigned short, (__bf16)f);
}
__device__ __forceinline__ unsigned pack2(float a, float b){
  return (unsigned)f2b(a) | ((unsigned)f2b(b)<<16);
}

template<int ACT>  // 0 none, 1 leaky-relu(0.2), 2 tanh
__device__ __forceinline__ float actf(float v){
  if constexpr (ACT==1) return v>0.f ? v : 0.2f*v;
  else if constexpr (ACT==2) return 1.f - 2.f/(__expf(2.f*v)+1.f);
  else return v;
}

// async 8KB weight tile: pre-swizzled global bf16 -> linear LDS (= swizzled tile)
__device__ __forceinline__ void glds16(const void* g, void* l){
  __builtin_amdgcn_global_load_lds(
      (const __attribute__((address_space(1))) unsigned int*)g,
      (__attribute__((address_space(3))) unsigned int*)l, 16, 0, 0);
}
__device__ __forceinline__ void stageW(const char* Wsrc, char* WS, int t){
  const int w = t>>6, l = t&63;
  glds16(Wsrc + w*1024 + l*16,        WS + w*1024);
  glds16(Wsrc + 4096 + w*1024 + l*16, WS + 4096 + w*1024);
}
__device__ __forceinline__ void stageWH(const char* Wsrc, char* WS, int t){  // 4KB
  const int w = t>>6, l = t&63;
  glds16(Wsrc + w*1024 + l*16, WS + w*1024);
}

// Swizzled 64x64 bf16 tile fragment read (16B, conflict-free)
__device__ __forceinline__ bf16x8 fragld(const char* buf, int row, int kb){
  const int byte = row*128 + (kb ^ ((row&7)<<4));
  return __builtin_bit_cast(bf16x8, *reinterpret_cast<const uint4v*>(buf + byte));
}

// stage x[b] (f32 global) -> swizzled bf16 LDS tile
__device__ __forceinline__ void stageX(const float* __restrict__ G, char* L){
  const int t = threadIdx.x;
  #pragma unroll
  for(int j=0;j<4;j++){
    const int f4 = t + 256*j;
    const float4 v = reinterpret_cast<const float4*>(G)[f4];
    const int row = f4 >> 4, col = (f4 & 15) * 4;
    uint2 pk; pk.x = pack2(v.x, v.y); pk.y = pack2(v.z, v.w);
    *reinterpret_cast<uint2*>(L + row*128 + ((2*col) ^ ((row&7)<<4))) = pk;
  }
}

// C = ACT(A @ Bt^T + bias). TST: store transposed. QB: emit qb[row]=qq_row.bkw
template<int ACT, bool TST, bool QB>
__device__ __forceinline__ void mm_core(const char* A, const char* Bt,
                                        const float* __restrict__ bias, char* C,
                                        const float* __restrict__ bkw, float* qbdst){
  const int t = threadIdx.x, fr = t & 15, fg = (t>>4)&3, wv = t>>6;
  f32x4 acc[4];
  #pragma unroll
  for(int n=0;n<4;n++) acc[n] = f32x4{0.f,0.f,0.f,0.f};
  const bf16x8 a0 = fragld(A, 16*wv+fr, fg*16);
  const bf16x8 a1 = fragld(A, 16*wv+fr, 64 + fg*16);
  #pragma unroll
  for(int n=0;n<4;n++){
    acc[n] = MFMA16(a0, fragld(Bt, n*16+fr, fg*16), acc[n]);
    acc[n] = MFMA16(a1, fragld(Bt, n*16+fr, 64 + fg*16), acc[n]);
  }
  float bz[4];
  #pragma unroll
  for(int n=0;n<4;n++) bz[n] = bias ? bias[n*16+fr] : 0.f;
  if constexpr (QB){
    float qp[4] = {0.f,0.f,0.f,0.f};
    #pragma unroll
    for(int n=0;n<4;n++){
      const float bkv = bkw[n*16+fr];
      #pragma unroll
      for(int r=0;r<4;r++) qp[r] = fmaf(acc[n][r]+bz[n], bkv, qp[r]);
    }
    #pragma unroll
    for(int m=1;m<16;m<<=1){
      #pragma unroll
      for(int r=0;r<4;r++) qp[r] += __shfl_xor(qp[r], m);
    }
    if(fr==0){
      #pragma unroll
      for(int r=0;r<4;r++) qbdst[16*wv + 4*fg + r] = qp[r];
    }
  }
  if constexpr (!TST){
    #pragma unroll
    for(int n=0;n<4;n++){
      #pragma unroll
      for(int r=0;r<4;r++){
        const int R = 16*wv + 4*fg + r;
        const int byte = R*128 + ((2*(n*16+fr)) ^ ((R&7)<<4));
        *reinterpret_cast<unsigned short*>(C + byte) = f2b(actf<ACT>(acc[n][r] + bz[n]));
      }
    }
  } else {
    #pragma unroll
    for(int n=0;n<4;n++){
      const int c = n*16 + fr;
      uint2 pk;
      pk.x = pack2(actf<ACT>(acc[n][0]+bz[n]), actf<ACT>(acc[n][1]+bz[n]));
      pk.y = pack2(actf<ACT>(acc[n][2]+bz[n]), actf<ACT>(acc[n][3]+bz[n]));
      *reinterpret_cast<uint2*>(C + c*128 + ((2*(16*wv + 4*fg)) ^ ((c&7)<<4))) = pk;
    }
  }
}

// MODE 0: P=softmax(s*SCALE). MODE 1/2: consensus, mask mg / 1-mg, P=softmax*mask.
template<int MODE>
__device__ __forceinline__ void score_softmax(const char* Aq, const char* Bk, char* P,
                                              const float* rs, const float* as_,
                                              const float* qb){
  const int t = threadIdx.x, fr = t & 15, fg = (t>>4)&3, wv = t>>6;
  f32x4 acc[4];
  #pragma unroll
  for(int n=0;n<4;n++) acc[n] = f32x4{0.f,0.f,0.f,0.f};
  const bf16x8 a0 = fragld(Aq, 16*wv+fr, fg*16);
  const bf16x8 a1 = fragld(Aq, 16*wv+fr, 64 + fg*16);
  #pragma unroll
  for(int n=0;n<4;n++){
    acc[n] = MFMA16(a0, fragld(Bk, n*16+fr, fg*16), acc[n]);
    acc[n] = MFMA16(a1, fragld(Bk, n*16+fr, 64 + fg*16), acc[n]);
  }
  float rc[4], aR[4], giR[4], qR[4];
  if constexpr (MODE != 0){
    #pragma unroll
    for(int n=0;n<4;n++) rc[n] = rs[n*16+fr];
    #pragma unroll
    for(int r=0;r<4;r++){
      const int R = 16*wv + 4*fg + r;
      aR[r] = as_[R];
      giR[r] = (rs[R] > aR[r]) ? 1.f : 0.f;
      qR[r] = qb[R];
    }
    #pragma unroll
    for(int n=0;n<4;n++){
      #pragma unroll
      for(int r=0;r<4;r++){
        float mv = (giR[r] != 0.f || rc[n] > aR[r]) ? 1.f : 0.f;
        if constexpr (MODE==2) mv = 1.f - mv;
        acc[n][r] = (mv*acc[n][r] + qR[r])*SCALE;
      }
    }
  }
  float mx[4];
  #pragma unroll
  for(int r=0;r<4;r++)
    mx[r] = fmaxf(fmaxf(acc[0][r],acc[1][r]), fmaxf(acc[2][r],acc[3][r]));
  #pragma unroll
  for(int m=1;m<16;m<<=1){
    #pragma unroll
    for(int r=0;r<4;r++) mx[r] = fmaxf(mx[r], __shfl_xor(mx[r], m));
  }
  float sm[4] = {0.f,0.f,0.f,0.f};
  #pragma unroll
  for(int n=0;n<4;n++){
    #pragma unroll
    for(int r=0;r<4;r++){
      const float e = __expf(MODE==0 ? (acc[n][r]-mx[r])*SCALE : (acc[n][r]-mx[r]));
      acc[n][r] = e; sm[r] += e;
    }
  }
  #pragma unroll
  for(int m=1;m<16;m<<=1){
    #pragma unroll
    for(int r=0;r<4;r++) sm[r] += __shfl_xor(sm[r], m);
  }
  float ri[4];
  #pragma unroll
  for(int r=0;r<4;r++) ri[r] = 1.f/sm[r];
  #pragma unroll
  for(int n=0;n<4;n++){
    #pragma unroll
    for(int r=0;r<4;r++){
      float val = acc[n][r]*ri[r];
      if constexpr (MODE != 0){
        float mv = (giR[r] != 0.f || rc[n] > aR[r]) ? 1.f : 0.f;
        if constexpr (MODE==2) mv = 1.f - mv;
        val *= mv;
      }
      const int R = 16*wv + 4*fg + r;
      const int byte = R*128 + ((2*(n*16+fr)) ^ ((R&7)<<4));
      *reinterpret_cast<unsigned short*>(P + byte) = f2b(val);
    }
  }
}

__device__ __forceinline__ void heads(const char* O1, const char* O2, const char* HW,
                                      const Params& p, int b){
  const int t = threadIdx.x, fr = t & 15, fg = (t>>4)&3, wv = t>>6;
  f32x4 acc = {0.f,0.f,0.f,0.f};
  #pragma unroll
  for(int kt=0;kt<4;kt++){
    const bf16x8 af = fragld(kt<2 ? O1 : O2, 16*wv+fr, (kt&1)*64 + fg*16);
    const int byte = fr*256 + (((kt*64) + fg*16) ^ ((fr&7)<<4));
    const bf16x8 bf_ = __builtin_bit_cast(bf16x8, *reinterpret_cast<const uint4v*>(HW + byte));
    acc = MFMA16(af, bf_, acc);
  }
  const float bz = (fr < 8) ? p.mean_b[fr] : p.ls_b[fr-8];
  #pragma unroll
  for(int r=0;r<4;r++){
    const int R = 16*wv + 4*fg + r;
    const int g = (b*64 + R)*8;
    float v = acc[r] + bz;
    if(fr < 8){
      p.out[g + fr] = v;
    } else {
      v = fminf(fmaxf(v, -20.f), 2.f);
      p.out[p.std_off + g + (fr-8)] = __expf(v);
    }
  }
}

#define BAR() __syncthreads()

__global__ __launch_bounds__(256,3) void rap_kernel(Params p){
  __shared__ __align__(16) char B0[8192];
  __shared__ __align__(16) char B1[8192];
  __shared__ __align__(16) char B2[8192];
  __shared__ __align__(16) char B3[8192];
  __shared__ __align__(16) char WSa[8192];
  __shared__ __align__(16) char WSb[8192];
  __shared__ float rnd_s[64], a_s[64], qb1_s[64], qb2_s[64];
  const int b = blockIdx.x, t = threadIdx.x;
  const char* ws = p.ws;
  const float* FB = reinterpret_cast<const float*>(ws + WS_BIAS);

  stageW(ws + 0*8192, WSa, t);                       // embed_w -> WSa
  if(t < 64){
    rnd_s[t] = p.rnd[b*64 + t];
    a_s[t]   = p.rnd[b*64 + p.idx[b*64 + t]];
  }
  stageX(p.x + (size_t)b*4096, B0);
  BAR();                                                              // x, embed ready
  stageW(ws + 1*8192, WSb, t);
  mm_core<1,false,false>(B0, WSa, p.embed_b, B1, nullptr, nullptr);   // E (lrelu)
  BAR();
  stageW(ws + 2*8192, WSa, t);
  mm_core<0,false,false>(B1, WSb, p.ia_bq, B0, nullptr, nullptr);     // Q
  BAR();
  stageW(ws + 3*8192, WSb, t);
  mm_core<0,false,false>(B1, WSa, p.ia_bk, B2, nullptr, nullptr);     // K
  BAR();
  stageW(ws + 4*8192, WSa, t);
  mm_core<0,true ,false>(B1, WSb, p.ia_bv, B3, nullptr, nullptr);     // V^T
  BAR();
  score_softmax<0>(B0, B2, B0, rnd_s, a_s, nullptr);                  // P (over Q)
  BAR();
  stageW(ws + 5*8192, WSb, t);
  mm_core<0,false,false>(B0, B3, nullptr, B2, nullptr, nullptr);      // ATT0 = P@V (over K)
  BAR();
  mm_core<2,false,false>(B2, WSa, p.ia_bo, B1, nullptr, nullptr);     // ATT = tanh (over E)
  BAR();
  stageW(ws + 6*8192, WSa, t);
  mm_core<0,false,true >(B1, WSb, FB+0*64, B0, p.c1_bk, qb1_s);       // QQ1 + qb1 (over P)
  BAR();
  stageW(ws + 7*8192, WSb, t);
  mm_core<0,false,false>(B1, WSa, FB+1*64, B2, nullptr, nullptr);     // KM1 (over ATT0)
  BAR();
  stageW(ws + 8*8192, WSa, t);
  mm_core<0,true ,false>(B1, WSb, FB+2*64, B3, nullptr, nullptr);     // VM1^T (over V)
  BAR();
  score_softmax<1>(B0, B2, B0, rnd_s, a_s, qb1_s);                    // P1 (over QQ1)
  BAR();
  stageW(ws + 9*8192, WSb, t);
  mm_core<0,false,false>(B0, B3, p.c1_bv, B2, nullptr, nullptr);      // CTX1 (over KM1)
  BAR();
  mm_core<1,false,false>(B2, WSa, p.c1_bo, B0, nullptr, nullptr);     // O1 lrelu (over P1)
  BAR();
  stageW(ws + 10*8192, WSa, t);
  mm_core<0,false,true >(B1, WSb, FB+3*64, B2, p.c2_bk, qb2_s);       // QQ2 + qb2 (over CTX1)
  BAR();
  stageW(ws + 11*8192, WSb, t);
  mm_core<0,true ,false>(B1, WSa, FB+4*64, B3, nullptr, nullptr);     // VM2^T (over VM1)
  BAR();
  stageW(ws + 12*8192, WSa, t);
  mm_core<0,false,false>(B1, WSb, FB+5*64, B1, nullptr, nullptr);     // KM2 (in-place over ATT)
  BAR();
  score_softmax<2>(B2, B1, B2, rnd_s, a_s, qb2_s);                    // P2 (over QQ2)
  BAR();
  stageWH(ws + WS_HEAD, WSb, t);
  mm_core<0,false,false>(B2, B3, p.c2_bv, B1, nullptr, nullptr);      // CTX2 (over KM2)
  BAR();
  mm_core<1,false,false>(B1, WSa, p.c2_bo, B3, nullptr, nullptr);     // O2 lrelu (over VM2)
  BAR();
  heads(B0, B3, WSb, p, b);
}

} // namespace

extern "C" void kernel_launch(void* const* d_in, const int* in_sizes, int n_in,
                              void* d_out, int out_size, void* d_ws, size_t ws_size,
                              hipStream_t stream){
  (void)n_in; (void)out_size; (void)ws_size;
  const float* x       = (const float*)d_in[0];
  const float* rnd     = (const float*)d_in[1];
  const int*   idx     = (const int*)  d_in[2];
  const float* embed_w = (const float*)d_in[3];  const float* embed_b = (const float*)d_in[4];
  const float* ia_wq = (const float*)d_in[5];  const float* ia_bq = (const float*)d_in[6];
  const float* ia_wk = (const float*)d_in[7];  const float* ia_bk = (const float*)d_in[8];
  const float* ia_wv = (const float*)d_in[9];  const float* ia_bv = (const float*)d_in[10];
  const float* ia_wo = (const float*)d_in[11]; const float* ia_bo = (const float*)d_in[12];
  const float* c1_wq = (const float*)d_in[13]; const float* c1_bq = (const float*)d_in[14];
  const float* c1_wk = (const float*)d_in[15]; const float* c1_bk = (const float*)d_in[16];
  const float* c1_wv = (const float*)d_in[17]; const float* c1_bv = (const float*)d_in[18];
  const float* c1_wo = (const float*)d_in[19]; const float* c1_bo = (const float*)d_in[20];
  const float* c2_wq = (const float*)d_in[21]; const float* c2_bq = (const float*)d_in[22];
  const float* c2_wk = (const float*)d_in[23]; const float* c2_bk = (const float*)d_in[24];
  const float* c2_wv = (const float*)d_in[25]; const float* c2_bv = (const float*)d_in[26];
  const float* c2_wo = (const float*)d_in[27]; const float* c2_bo = (const float*)d_in[28];
  const float* msg_w = (const float*)d_in[29]; const float* msg_b = (const float*)d_in[30];
  const float* st_w  = (const float*)d_in[31]; const float* st_b  = (const float*)d_in[32];
  const float* mean_w= (const float*)d_in[33]; const float* mean_b= (const float*)d_in[34];
  const float* ls_w  = (const float*)d_in[35]; const float* ls_b  = (const float*)d_in[36];

  PrepParams q;
  const float* psrc[7] = {embed_w, ia_wq, ia_wk, ia_wv, ia_wo, c1_wo, c2_wo};
  const int    pslot[7] = {0, 1, 2, 3, 4, 8, 12};
  for(int i=0;i<7;i++){ q.plain_src[i]=psrc[i]; q.plain_slot[i]=pslot[i]; }
  const float* fA[6]  = {c1_wq, c1_wk, c1_wv, c2_wq, c2_wv, c2_wk};
  const float* fBm[6] = {st_w,  msg_w, msg_w, st_w,  msg_w, msg_w};
  const float* fb[6]  = {st_b,  msg_b, msg_b, st_b,  msg_b, msg_b};
  const float* fx[6]  = {c1_bq, nullptr, nullptr, c2_bq, nullptr, nullptr};
  const int    fslot[6] = {5, 6, 7, 9, 10, 11};
  for(int i=0;i<6;i++){ q.fuse_A[i]=fA[i]; q.fuse_B[i]=fBm[i]; q.fuse_b[i]=fb[i];
                        q.fuse_extra[i]=fx[i]; q.fuse_slot[i]=fslot[i]; }
  q.mean_w = mean_w; q.ls_w = ls_w; q.ws = (char*)d_ws;
  prep_kernel<<<dim3(14), dim3(256), 0, stream>>>(q);

  Params p;
  p.x = x; p.rnd = rnd; p.idx = idx;
  p.embed_b = embed_b; p.ia_bq = ia_bq; p.ia_bk = ia_bk; p.ia_bv = ia_bv; p.ia_bo = ia_bo;
  p.c1_bk = c1_bk; p.c1_bv = c1_bv; p.c1_bo = c1_bo;
  p.c2_bk = c2_bk; p.c2_bv = c2_bv; p.c2_bo = c2_bo;
  p.mean_b = mean_b; p.ls_b = ls_b;
  p.ws = (const char*)d_ws;
  p.out = (float*)d_out;
  const int Bb = in_sizes[0] / 4096;   // x is [B,64,64]
  p.std_off = Bb * 64 * 8;
  rap_kernel<<<dim3(Bb), dim3(256), 0, stream>>>(p);
}